// Round 1
// baseline (785.329 us; speedup 1.0000x reference)
//
#include <hip/hip_runtime.h>
#include <stdint.h>

#define B_   32
#define S_   4096
#define HID_ 5120
#define H_   16
#define DN_  128
#define DR_  64
#define DV_  128
#define QL_  1536
#define KL_  512
#define KC_  576            // KL + DR
#define NQKV_ 2112          // QL + KL + DR
#define NQB_  3072          // H*(DN+DR)
#define EPS_ 1e-6f
#define SCALE_ 0.07216878364870323f   // (DN+DR)^-0.5

typedef __attribute__((ext_vector_type(4))) float f32x4;
typedef __attribute__((ext_vector_type(8))) short s16x8;
typedef __attribute__((ext_vector_type(4))) unsigned short u16x4;

__device__ __forceinline__ unsigned short f2bf(float f) {
  union { float f; unsigned u; } v; v.f = f;
  unsigned r = v.u + 0x7fffu + ((v.u >> 16) & 1u);
  return (unsigned short)(r >> 16);
}

// ---------------- K0: transpose hidden (B x K) -> (K x B) ----------------
__global__ void transpose_k(const float* __restrict__ X, float* __restrict__ XT, int K) {
  int k = blockIdx.x * blockDim.x + threadIdx.x;
  if (k >= K) return;
#pragma unroll
  for (int b = 0; b < B_; ++b) XT[(size_t)k * B_ + b] = X[(size_t)b * K + k];
}

// ------------- split-K GEMM: P[ks][b][n] = sum_{k in slice} AT[k][b]*W[k][n] -------------
__global__ void gemm_part(const float* __restrict__ AT, const float* __restrict__ W,
                          float* __restrict__ P, int N, int TK) {
  int n = blockIdx.x * 64 + threadIdx.x;
  int k0 = blockIdx.y * TK;
  float acc[B_];
#pragma unroll
  for (int b = 0; b < B_; ++b) acc[b] = 0.f;
  const float* w  = W  + (size_t)k0 * N + n;
  const float* ak = AT + (size_t)k0 * B_;
  for (int k = 0; k < TK; ++k) {
    float wv = *w;
#pragma unroll
    for (int b = 0; b < B_; ++b) acc[b] = fmaf(ak[b], wv, acc[b]);
    w += N; ak += B_;
  }
  float* p = P + ((size_t)blockIdx.y * B_) * N + n;
#pragma unroll
  for (int b = 0; b < B_; ++b) p[(size_t)b * N] = acc[b];
}

// ---------------- K2a: reduce qkv partials, rmsnorms, rope(k_pe) ----------------
__global__ void k2a(const float* __restrict__ P1, const float* __restrict__ qw,
                    const float* __restrict__ kvw, const int* __restrict__ pos,
                    float* __restrict__ qnT, float* __restrict__ latent_n,
                    float* __restrict__ kpe_rot, float* __restrict__ cs_buf) {
  int b = blockIdx.x, t = threadIdx.x;
  __shared__ float row[NQKV_];
  __shared__ float red[256], red2[256];
  float sq = 0.f, sl = 0.f;
  for (int n = t; n < NQKV_; n += 256) {
    float s = 0.f;
    for (int ks = 0; ks < 32; ++ks) s += P1[((size_t)ks * B_ + b) * NQKV_ + n];
    row[n] = s;
    if (n < QL_) sq += s * s;
    else if (n < QL_ + KL_) sl += s * s;
  }
  red[t] = sq; red2[t] = sl;
  __syncthreads();
  for (int off = 128; off > 0; off >>= 1) {
    if (t < off) { red[t] += red[t + off]; red2[t] += red2[t + off]; }
    __syncthreads();
  }
  float rq = 1.0f / sqrtf(red[0]  / QL_ + EPS_);
  float rl = 1.0f / sqrtf(red2[0] / KL_ + EPS_);
  for (int n = t; n < QL_; n += 256) qnT[(size_t)n * B_ + b] = row[n] * rq * qw[n];
  for (int n = t; n < KL_; n += 256) latent_n[(size_t)b * KL_ + n] = row[QL_ + n] * rl * kvw[n];
  if (t < 32) {
    double inv = exp(-((double)t / 32.0) * log(10000.0));
    float fr = (float)pos[b] * (float)inv;
    float c = (float)cos((double)fr), s = (float)sin((double)fr);
    cs_buf[(b * 32 + t) * 2] = c; cs_buf[(b * 32 + t) * 2 + 1] = s;
    float x1 = row[QL_ + KL_ + 2 * t], x2 = row[QL_ + KL_ + 2 * t + 1];
    kpe_rot[b * DR_ + 2 * t]     = x1 * c - x2 * s;
    kpe_rot[b * DR_ + 2 * t + 1] = x2 * c + x1 * s;
  }
}

// ---------------- K2c: reduce q partials, rope(q_pe), q_abs = q_nope @ w_kc ----------------
__global__ void k2c(const float* __restrict__ P2, const float* __restrict__ w_kc,
                    const float* __restrict__ cs_buf, unsigned short* __restrict__ q_cat) {
  int h = blockIdx.x, b = blockIdx.y, t = threadIdx.x;  // 64 threads
  __shared__ float qh[192];
  for (int j = t; j < 192; j += 64) {
    float s = 0.f;
    int col = h * 192 + j;
    for (int ks = 0; ks < 16; ++ks) s += P2[((size_t)ks * B_ + b) * NQB_ + col];
    qh[j] = s;
  }
  __syncthreads();
  if (t < 32) {
    float c = cs_buf[(b * 32 + t) * 2], s = cs_buf[(b * 32 + t) * 2 + 1];
    float x1 = qh[DN_ + 2 * t], x2 = qh[DN_ + 2 * t + 1];
    qh[DN_ + 2 * t]     = x1 * c - x2 * s;
    qh[DN_ + 2 * t + 1] = x2 * c + x1 * s;
  }
  __syncthreads();
  float acc[8];
#pragma unroll
  for (int i = 0; i < 8; ++i) acc[i] = 0.f;
  const float* wk = w_kc + (size_t)h * DN_ * KL_;
  for (int d = 0; d < DN_; ++d) {
    float qd = qh[d];
#pragma unroll
    for (int i = 0; i < 8; ++i)
      acc[i] = fmaf(qd, wk[(size_t)d * KL_ + t + 64 * i], acc[i]);
  }
  unsigned short* qc = q_cat + ((size_t)b * H_ + h) * KC_;
#pragma unroll
  for (int i = 0; i < 8; ++i) qc[t + 64 * i] = f2bf(acc[i] * SCALE_);
  qc[KL_ + t] = f2bf(qh[DN_ + t] * SCALE_);
}

// ---------------- K3: flash attention (bf16 MFMA, online softmax) ----------------
#define LP_ 584          // LDS row pitch (bf16 elems): 16B-aligned rows, 2-way max on b128 frags
#define CHUNK_ 256
#define TR_ 32           // rows per tile
#define NTL_ 8           // tiles per chunk == c-tiles per wave (coincidentally both 8)

__global__ __launch_bounds__(256) void attn(
    const float* __restrict__ cache_l, const float* __restrict__ cache_r,
    const float* __restrict__ latent_n, const float* __restrict__ kpe_rot,
    const unsigned short* __restrict__ q_cat,
    float* __restrict__ ws_acc, float* __restrict__ ws_ml) {
  int chunk = blockIdx.x, b = blockIdx.y;
  int t = threadIdx.x, wave = t >> 6, lane = t & 63;
  int quad = lane >> 4, lo = lane & 15;

  __shared__ __attribute__((aligned(16))) unsigned short Lt[TR_ * LP_];
  __shared__ __attribute__((aligned(16))) unsigned short pb[4][H_ * TR_];

  // A-frags: A[m=h=lane&15][k=ks*32+quad*8+j], SCALE pre-folded
  s16x8 af[18];
  const unsigned short* qc = q_cat + ((size_t)b * H_ + lo) * KC_;
#pragma unroll
  for (int ks = 0; ks < 18; ++ks) af[ks] = *(const s16x8*)(qc + ks * 32 + quad * 8);

  f32x4 accc[NTL_];                 // ctx: c = wave*128+nt*16+lo, h = quad*4+reg
#pragma unroll
  for (int i = 0; i < NTL_; ++i) accc[i] = (f32x4){0.f, 0.f, 0.f, 0.f};
  float m_run[4], l_run[4];
#pragma unroll
  for (int r = 0; r < 4; ++r) { m_run[r] = -3.0e38f; l_run[r] = 0.f; }

  int r8 = t >> 3, u = t & 7;       // staging map: 8 threads per row

#pragma unroll 1
  for (int tile = 0; tile < NTL_; ++tile) {
    int s = chunk * CHUNK_ + tile * TR_ + r8;
    const float* rl = cache_l + ((size_t)b * S_ + s) * KL_;
    const float* rr = cache_r + ((size_t)b * S_ + s) * DR_;
    if (s == S_ - 1) { rl = latent_n + (size_t)b * KL_; rr = kpe_rot + (size_t)b * DR_; }
    __syncthreads();   // previous tile's reads done before overwrite
#pragma unroll
    for (int j = 0; j < 18; ++j) {
      int c = u * 4 + j * 32;
      const float* src = (j < 16) ? (rl + c) : (rr + (c - 512));
      float4 v = *(const float4*)src;
      u16x4 o; o.x = f2bf(v.x); o.y = f2bf(v.y); o.z = f2bf(v.z); o.w = f2bf(v.w);
      *(u16x4*)(&Lt[r8 * LP_ + c]) = o;
    }
    __syncthreads();
    // scores: D[h][r] = sum_c q[h][c]*L[r][c]; B[k=c][n=r] read row-major from Lt
    f32x4 sc0 = {0.f, 0.f, 0.f, 0.f}, sc1 = {0.f, 0.f, 0.f, 0.f};
#pragma unroll
    for (int ks = 0; ks < 18; ++ks) {
      s16x8 b0 = *(const s16x8*)(&Lt[lo * LP_ + ks * 32 + quad * 8]);
      s16x8 b1 = *(const s16x8*)(&Lt[(16 + lo) * LP_ + ks * 32 + quad * 8]);
      sc0 = __builtin_amdgcn_mfma_f32_16x16x32_bf16(af[ks], b0, sc0, 0, 0, 0);
      sc1 = __builtin_amdgcn_mfma_f32_16x16x32_bf16(af[ks], b1, sc1, 0, 0, 0);
    }
    // online softmax per wave (redundant across waves, identical results)
#pragma unroll
    for (int reg = 0; reg < 4; ++reg) {
      float s0 = sc0[reg], s1 = sc1[reg];
      float mt = fmaxf(s0, s1);
#pragma unroll
      for (int m = 1; m < 16; m <<= 1) mt = fmaxf(mt, __shfl_xor(mt, m, 64));
      float mn = fmaxf(m_run[reg], mt);
      float alpha = __expf(m_run[reg] - mn);
      m_run[reg] = mn;
      float p0 = __expf(s0 - mn), p1 = __expf(s1 - mn);
      float lt = p0 + p1;
#pragma unroll
      for (int m = 1; m < 16; m <<= 1) lt += __shfl_xor(lt, m, 64);
      l_run[reg] = l_run[reg] * alpha + lt;
#pragma unroll
      for (int i = 0; i < NTL_; ++i) accc[i][reg] *= alpha;
      int h = quad * 4 + reg;
      pb[wave][h * TR_ + lo]      = f2bf(p0);
      pb[wave][h * TR_ + 16 + lo] = f2bf(p1);
    }
    // ctx: D[h][c] += sum_s P[h][s]*L[s][c];  A from pb (wave-private), B col-reads from Lt
    s16x8 ap = *(const s16x8*)(&pb[wave][lo * TR_ + quad * 8]);
#pragma unroll
    for (int nt = 0; nt < NTL_; ++nt) {
      int c = wave * 128 + nt * 16 + lo;
      s16x8 bv;
#pragma unroll
      for (int j = 0; j < 8; ++j) bv[j] = (short)Lt[(quad * 8 + j) * LP_ + c];
      accc[nt] = __builtin_amdgcn_mfma_f32_16x16x32_bf16(ap, bv, accc[nt], 0, 0, 0);
    }
  }
  // write chunk partials
  float* accp = ws_acc + (((size_t)b * 16 + chunk) * H_) * KL_;
#pragma unroll
  for (int nt = 0; nt < NTL_; ++nt) {
    int c = wave * 128 + nt * 16 + lo;
#pragma unroll
    for (int reg = 0; reg < 4; ++reg)
      accp[(size_t)(quad * 4 + reg) * KL_ + c] = accc[nt][reg];
  }
  if (wave == 0 && lo == 0) {
#pragma unroll
    for (int reg = 0; reg < 4; ++reg) {
      int h = quad * 4 + reg;
      ws_ml[(((size_t)b * 16 + chunk) * H_ + h) * 2 + 0] = m_run[reg];
      ws_ml[(((size_t)b * 16 + chunk) * H_ + h) * 2 + 1] = l_run[reg];
    }
  }
}

// ---------------- K4: combine chunks + ctx @ w_vc ----------------
__global__ void combine(const float* __restrict__ ws_acc, const float* __restrict__ ws_ml,
                        const float* __restrict__ w_vc, float* __restrict__ o_vT) {
  int h = blockIdx.x, b = blockIdx.y, t = threadIdx.x;
  __shared__ float sm[16], sl[16];
  __shared__ float ctx[KL_];
  __shared__ float ps[256];
  if (t < 16) {
    sm[t] = ws_ml[(((size_t)b * 16 + t) * H_ + h) * 2];
    sl[t] = ws_ml[(((size_t)b * 16 + t) * H_ + h) * 2 + 1];
  }
  __syncthreads();
  float M = -3e38f;
#pragma unroll
  for (int i = 0; i < 16; ++i) M = fmaxf(M, sm[i]);
  float wkk[16]; float Lsum = 0.f;
#pragma unroll
  for (int i = 0; i < 16; ++i) { wkk[i] = __expf(sm[i] - M); Lsum += wkk[i] * sl[i]; }
  float invL = 1.0f / Lsum;
  for (int c = t; c < KL_; c += 256) {
    float s = 0.f;
#pragma unroll
    for (int i = 0; i < 16; ++i)
      s += wkk[i] * ws_acc[(((size_t)b * 16 + i) * H_ + h) * KL_ + c];
    ctx[c] = s * invL;
  }
  __syncthreads();
  int v = t & 127, half = t >> 7;
  const float* wv = w_vc + (size_t)h * KL_ * DV_;
  float s = 0.f;
  for (int k = half * 256; k < half * 256 + 256; ++k)
    s = fmaf(ctx[k], wv[(size_t)k * DV_ + v], s);
  ps[t] = s;
  __syncthreads();
  if (t < 128) o_vT[((size_t)h * DV_ + t) * B_ + b] = ps[t] + ps[t + 128];
}

// ---------------- K6: reduce split-K partials of out proj ----------------
__global__ void reduce_out(const float* __restrict__ P, float* __restrict__ out) {
  int i = blockIdx.x * 256 + threadIdx.x;   // 32*5120
  float s = 0.f;
#pragma unroll
  for (int ks = 0; ks < 16; ++ks) s += P[(size_t)ks * (B_ * HID_) + i];
  out[i] = s;
}

extern "C" void kernel_launch(void* const* d_in, const int* in_sizes, int n_in,
                              void* d_out, int out_size, void* d_ws, size_t ws_size,
                              hipStream_t stream) {
  const float* hs    = (const float*)d_in[0];
  const int*   pos   = (const int*)d_in[1];
  const float* cl    = (const float*)d_in[2];
  const float* cr    = (const float*)d_in[3];
  const float* w_qkv = (const float*)d_in[4];
  const float* qnw   = (const float*)d_in[5];
  const float* w_qb  = (const float*)d_in[6];
  const float* kvnw  = (const float*)d_in[7];
  const float* w_kc  = (const float*)d_in[8];
  const float* w_vc  = (const float*)d_in[9];
  const float* w_o   = (const float*)d_in[10];
  float* out = (float*)d_out;

  char* ws = (char*)d_ws;
  float* big = (float*)ws;                              // reused: P1 / P2 / ws_acc / P5
  size_t P0 = 16777216;                                 // persistent region
  float* hsT      = (float*)(ws + P0);
  float* qnT      = (float*)(ws + P0 + 655360);
  float* latent_n = (float*)(ws + P0 + 851968);
  float* kpe_rot  = (float*)(ws + P0 + 917504);
  float* cs_buf   = (float*)(ws + P0 + 925696);
  unsigned short* q_cat = (unsigned short*)(ws + P0 + 933888);
  float* ws_ml    = (float*)(ws + P0 + 1523712);
  float* o_vT     = (float*)(ws + P0 + 1589248);

  transpose_k<<<20, 256, 0, stream>>>(hs, hsT, HID_);
  gemm_part<<<dim3(33, 32), 64, 0, stream>>>(hsT, w_qkv, big, NQKV_, 160);
  k2a<<<32, 256, 0, stream>>>(big, qnw, kvnw, pos, qnT, latent_n, kpe_rot, cs_buf);
  gemm_part<<<dim3(48, 16), 64, 0, stream>>>(qnT, w_qb, big, NQB_, 96);
  k2c<<<dim3(16, 32), 64, 0, stream>>>(big, w_kc, cs_buf, q_cat);
  attn<<<dim3(16, 32), 256, 0, stream>>>(cl, cr, latent_n, kpe_rot, q_cat, big, ws_ml);
  combine<<<dim3(16, 32), 256, 0, stream>>>(big, ws_ml, w_vc, o_vT);
  gemm_part<<<dim3(80, 16), 64, 0, stream>>>(o_vT, w_o, big, HID_, 128);
  reduce_out<<<640, 256, 0, stream>>>(big, out);
}

// Round 2
// 696.898 us; speedup vs baseline: 1.1269x; 1.1269x over previous
//
#include <hip/hip_runtime.h>
#include <stdint.h>

#define B_   32
#define S_   4096
#define HID_ 5120
#define H_   16
#define DN_  128
#define DR_  64
#define DV_  128
#define QL_  1536
#define KL_  512
#define KC_  576            // KL + DR
#define NQKV_ 2112          // QL + KL + DR
#define NQB_  3072          // H*(DN+DR)
#define EPS_ 1e-6f
#define SCALE_ 0.07216878364870323f   // (DN+DR)^-0.5

typedef __attribute__((ext_vector_type(4))) float f32x4;
typedef __attribute__((ext_vector_type(8))) short s16x8;
typedef __attribute__((ext_vector_type(4))) unsigned short u16x4;

__device__ __forceinline__ unsigned short f2bf(float f) {
  union { float f; unsigned u; } v; v.f = f;
  unsigned r = v.u + 0x7fffu + ((v.u >> 16) & 1u);
  return (unsigned short)(r >> 16);
}

// ---------------- zero3: init atomic-accumulation buffers ----------------
__global__ void zero3(float* a, int na, float* b, int nb, float* c, int nc) {
  int i = blockIdx.x * 256 + threadIdx.x;
  if (i < na) a[i] = 0.f;
  if (i < nb) b[i] = 0.f;
  if (i < nc) c[i] = 0.f;
}

// ------------- split-K GEMM, atomic accumulate: O[b][n] += sum_{k in slice} A[b][k]*W[k][n]
// A [32][K] natural layout; staged to LDS transposed. 256 thr = 256 n-cols.
template<int K, int TK, int N>
__global__ __launch_bounds__(256) void gemm_at(const float* __restrict__ A,
                                               const float* __restrict__ W,
                                               float* __restrict__ O) {
  constexpr int PITCH = 36;               // +4 pad: bank stride 4, 16B-aligned rows
  __shared__ float As[TK * PITCH];
  int t = threadIdx.x;
  int k0 = blockIdx.y * TK;
  // stage A[0..31][k0..k0+TK) -> As[k][b], coalesced float4 reads
  constexpr int NV = TK * 32 / 4 / 256;   // float4s per thread
#pragma unroll
  for (int i = 0; i < NV; ++i) {
    int idx = t + 256 * i;                // over (b, k4)
    int b = idx / (TK / 4), k4 = idx % (TK / 4);
    float4 v = *(const float4*)(A + (size_t)b * K + k0 + k4 * 4);
    As[(k4 * 4 + 0) * PITCH + b] = v.x;
    As[(k4 * 4 + 1) * PITCH + b] = v.y;
    As[(k4 * 4 + 2) * PITCH + b] = v.z;
    As[(k4 * 4 + 3) * PITCH + b] = v.w;
  }
  __syncthreads();
  int n = blockIdx.x * 256 + t;
  bool valid = (n < N);
  int nc = valid ? n : 0;
  float acc[32];
#pragma unroll
  for (int b = 0; b < 32; ++b) acc[b] = 0.f;
  const float* w = W + (size_t)k0 * N + nc;
#pragma unroll 4
  for (int k = 0; k < TK; ++k) {
    float wv = w[(size_t)k * N];
    const float* ar = As + k * PITCH;     // wave-uniform: b128 broadcast reads
#pragma unroll
    for (int b = 0; b < 32; ++b) acc[b] = fmaf(ar[b], wv, acc[b]);
  }
  if (valid) {
#pragma unroll
    for (int b = 0; b < 32; ++b) atomicAdd(O + (size_t)b * N + nc, acc[b]);
  }
}

// ---------------- k2a: rmsnorms on reduced qkv, rope(k_pe) ----------------
__global__ void k2a(const float* __restrict__ qkv, const float* __restrict__ qw,
                    const float* __restrict__ kvw, const int* __restrict__ pos,
                    float* __restrict__ qn, float* __restrict__ latent_n,
                    float* __restrict__ kpe_rot, float* __restrict__ cs_buf) {
  int b = blockIdx.x, t = threadIdx.x;
  __shared__ float row[NQKV_];
  __shared__ float red[256], red2[256];
  float sq = 0.f, sl = 0.f;
  for (int n = t; n < NQKV_; n += 256) {
    float s = qkv[(size_t)b * NQKV_ + n];
    row[n] = s;
    if (n < QL_) sq += s * s;
    else if (n < QL_ + KL_) sl += s * s;
  }
  red[t] = sq; red2[t] = sl;
  __syncthreads();
  for (int off = 128; off > 0; off >>= 1) {
    if (t < off) { red[t] += red[t + off]; red2[t] += red2[t + off]; }
    __syncthreads();
  }
  float rq = 1.0f / sqrtf(red[0]  / QL_ + EPS_);
  float rl = 1.0f / sqrtf(red2[0] / KL_ + EPS_);
  for (int n = t; n < QL_; n += 256) qn[(size_t)b * QL_ + n] = row[n] * rq * qw[n];
  for (int n = t; n < KL_; n += 256) latent_n[(size_t)b * KL_ + n] = row[QL_ + n] * rl * kvw[n];
  if (t < 32) {
    double inv = exp(-((double)t / 32.0) * log(10000.0));
    float fr = (float)pos[b] * (float)inv;
    float c = (float)cos((double)fr), s = (float)sin((double)fr);
    cs_buf[(b * 32 + t) * 2] = c; cs_buf[(b * 32 + t) * 2 + 1] = s;
    float x1 = row[QL_ + KL_ + 2 * t], x2 = row[QL_ + KL_ + 2 * t + 1];
    kpe_rot[b * DR_ + 2 * t]     = x1 * c - x2 * s;
    kpe_rot[b * DR_ + 2 * t + 1] = x2 * c + x1 * s;
  }
}

// ---------------- k2c: rope(q_pe), q_abs = q_nope @ w_kc ----------------
__global__ void k2c(const float* __restrict__ qb, const float* __restrict__ w_kc,
                    const float* __restrict__ cs_buf, unsigned short* __restrict__ q_cat) {
  int h = blockIdx.x, b = blockIdx.y, t = threadIdx.x;  // 64 threads
  __shared__ float qh[192];
  for (int j = t; j < 192; j += 64) qh[j] = qb[(size_t)b * NQB_ + h * 192 + j];
  __syncthreads();
  if (t < 32) {
    float c = cs_buf[(b * 32 + t) * 2], s = cs_buf[(b * 32 + t) * 2 + 1];
    float x1 = qh[DN_ + 2 * t], x2 = qh[DN_ + 2 * t + 1];
    qh[DN_ + 2 * t]     = x1 * c - x2 * s;
    qh[DN_ + 2 * t + 1] = x2 * c + x1 * s;
  }
  __syncthreads();
  float acc[8];
#pragma unroll
  for (int i = 0; i < 8; ++i) acc[i] = 0.f;
  const float* wk = w_kc + (size_t)h * DN_ * KL_;
  for (int d = 0; d < DN_; ++d) {
    float qd = qh[d];
#pragma unroll
    for (int i = 0; i < 8; ++i)
      acc[i] = fmaf(qd, wk[(size_t)d * KL_ + t + 64 * i], acc[i]);
  }
  unsigned short* qc = q_cat + ((size_t)b * H_ + h) * KC_;
#pragma unroll
  for (int i = 0; i < 8; ++i) qc[t + 64 * i] = f2bf(acc[i] * SCALE_);
  qc[KL_ + t] = f2bf(qh[DN_ + t] * SCALE_);
}

// ---------------- attn: flash attention (bf16 MFMA, online softmax) ----------------
#define LP_ 584          // LDS row pitch (bf16): 16B-aligned rows, 2-way max on b128 frags
#define CHUNK_ 256
#define TR_ 32
#define NTL_ 8

__global__ __launch_bounds__(256, 2) void attn(
    const float* __restrict__ cache_l, const float* __restrict__ cache_r,
    const float* __restrict__ latent_n, const float* __restrict__ kpe_rot,
    const unsigned short* __restrict__ q_cat,
    float* __restrict__ ws_acc, float* __restrict__ ws_ml) {
  int chunk = blockIdx.x, b = blockIdx.y;
  int t = threadIdx.x, wave = t >> 6, lane = t & 63;
  int quad = lane >> 4, lo = lane & 15;

  __shared__ __attribute__((aligned(16))) unsigned short Lt[TR_ * LP_];
  __shared__ __attribute__((aligned(16))) unsigned short pb[4][H_ * TR_];

  // A-frags: A[m=h=lane&15][k=ks*32+quad*8+j], SCALE pre-folded
  s16x8 af[18];
  const unsigned short* qc = q_cat + ((size_t)b * H_ + lo) * KC_;
#pragma unroll
  for (int ks = 0; ks < 18; ++ks) af[ks] = *(const s16x8*)(qc + ks * 32 + quad * 8);

  f32x4 accc[NTL_];                 // ctx: c = wave*128+nt*16+lo, h = quad*4+reg
#pragma unroll
  for (int i = 0; i < NTL_; ++i) accc[i] = (f32x4){0.f, 0.f, 0.f, 0.f};
  float m_run[4], l_run[4];
#pragma unroll
  for (int r = 0; r < 4; ++r) { m_run[r] = -3.0e38f; l_run[r] = 0.f; }

  int r8 = t >> 3, u = t & 7;       // staging map: 8 threads per row

  float4 v[18];                     // register prefetch buffer (72 VGPRs)
  auto load_tile = [&](int tile) {
    int s = chunk * CHUNK_ + tile * TR_ + r8;
    const float* rl = cache_l + ((size_t)b * S_ + s) * KL_;
    const float* rr = cache_r + ((size_t)b * S_ + s) * DR_;
    if (s == S_ - 1) { rl = latent_n + (size_t)b * KL_; rr = kpe_rot + (size_t)b * DR_; }
#pragma unroll
    for (int j = 0; j < 18; ++j) {
      int c = u * 4 + j * 32;
      v[j] = *(const float4*)((j < 16) ? (rl + c) : (rr + (c - 512)));
    }
  };
  load_tile(0);

#pragma unroll 1
  for (int tile = 0; tile < NTL_; ++tile) {
    __syncthreads();   // previous tile's LDS reads done before overwrite
#pragma unroll
    for (int j = 0; j < 18; ++j) {
      int c = u * 4 + j * 32;
      u16x4 o; o.x = f2bf(v[j].x); o.y = f2bf(v[j].y); o.z = f2bf(v[j].z); o.w = f2bf(v[j].w);
      *(u16x4*)(&Lt[r8 * LP_ + c]) = o;
    }
    if (tile + 1 < NTL_) load_tile(tile + 1);   // overlap next-tile HBM with compute
    __syncthreads();
    // scores: D[h][r] = sum_c q[h][c]*L[r][c]
    f32x4 sc0 = {0.f, 0.f, 0.f, 0.f}, sc1 = {0.f, 0.f, 0.f, 0.f};
#pragma unroll
    for (int ks = 0; ks < 18; ++ks) {
      s16x8 b0 = *(const s16x8*)(&Lt[lo * LP_ + ks * 32 + quad * 8]);
      s16x8 b1 = *(const s16x8*)(&Lt[(16 + lo) * LP_ + ks * 32 + quad * 8]);
      sc0 = __builtin_amdgcn_mfma_f32_16x16x32_bf16(af[ks], b0, sc0, 0, 0, 0);
      sc1 = __builtin_amdgcn_mfma_f32_16x16x32_bf16(af[ks], b1, sc1, 0, 0, 0);
    }
    // online softmax per wave (redundant across waves, identical results)
#pragma unroll
    for (int reg = 0; reg < 4; ++reg) {
      float s0 = sc0[reg], s1 = sc1[reg];
      float mt = fmaxf(s0, s1);
#pragma unroll
      for (int m = 1; m < 16; m <<= 1) mt = fmaxf(mt, __shfl_xor(mt, m, 64));
      float mn = fmaxf(m_run[reg], mt);
      float alpha = __expf(m_run[reg] - mn);
      m_run[reg] = mn;
      float p0 = __expf(s0 - mn), p1 = __expf(s1 - mn);
      float lt = p0 + p1;
#pragma unroll
      for (int m = 1; m < 16; m <<= 1) lt += __shfl_xor(lt, m, 64);
      l_run[reg] = l_run[reg] * alpha + lt;
#pragma unroll
      for (int i = 0; i < NTL_; ++i) accc[i][reg] *= alpha;
      int h = quad * 4 + reg;
      pb[wave][h * TR_ + lo]      = f2bf(p0);
      pb[wave][h * TR_ + 16 + lo] = f2bf(p1);
    }
    // ctx: D[h][c] += sum_s P[h][s]*L[s][c]
    s16x8 ap = *(const s16x8*)(&pb[wave][lo * TR_ + quad * 8]);
#pragma unroll
    for (int nt = 0; nt < NTL_; ++nt) {
      int c = wave * 128 + nt * 16 + lo;
      s16x8 bv;
#pragma unroll
      for (int j = 0; j < 8; ++j) bv[j] = (short)Lt[(quad * 8 + j) * LP_ + c];
      accc[nt] = __builtin_amdgcn_mfma_f32_16x16x32_bf16(ap, bv, accc[nt], 0, 0, 0);
    }
  }
  float* accp = ws_acc + (((size_t)b * 16 + chunk) * H_) * KL_;
#pragma unroll
  for (int nt = 0; nt < NTL_; ++nt) {
    int c = wave * 128 + nt * 16 + lo;
#pragma unroll
    for (int reg = 0; reg < 4; ++reg)
      accp[(size_t)(quad * 4 + reg) * KL_ + c] = accc[nt][reg];
  }
  if (wave == 0 && lo == 0) {
#pragma unroll
    for (int reg = 0; reg < 4; ++reg) {
      int h = quad * 4 + reg;
      ws_ml[(((size_t)b * 16 + chunk) * H_ + h) * 2 + 0] = m_run[reg];
      ws_ml[(((size_t)b * 16 + chunk) * H_ + h) * 2 + 1] = l_run[reg];
    }
  }
}

// ---------------- combine chunks + ctx @ w_vc ----------------
__global__ void combine(const float* __restrict__ ws_acc, const float* __restrict__ ws_ml,
                        const float* __restrict__ w_vc, float* __restrict__ o_v) {
  int h = blockIdx.x, b = blockIdx.y, t = threadIdx.x;
  __shared__ float sm[16], sl[16];
  __shared__ float ctx[KL_];
  __shared__ float ps[256];
  if (t < 16) {
    sm[t] = ws_ml[(((size_t)b * 16 + t) * H_ + h) * 2];
    sl[t] = ws_ml[(((size_t)b * 16 + t) * H_ + h) * 2 + 1];
  }
  __syncthreads();
  float M = -3e38f;
#pragma unroll
  for (int i = 0; i < 16; ++i) M = fmaxf(M, sm[i]);
  float wkk[16]; float Lsum = 0.f;
#pragma unroll
  for (int i = 0; i < 16; ++i) { wkk[i] = __expf(sm[i] - M); Lsum += wkk[i] * sl[i]; }
  float invL = 1.0f / Lsum;
  for (int c = t; c < KL_; c += 256) {
    float s = 0.f;
#pragma unroll
    for (int i = 0; i < 16; ++i)
      s += wkk[i] * ws_acc[(((size_t)b * 16 + i) * H_ + h) * KL_ + c];
    ctx[c] = s * invL;
  }
  __syncthreads();
  int vv = t & 127, half = t >> 7;
  const float* wv = w_vc + (size_t)h * KL_ * DV_;
  float s = 0.f;
  for (int k = half * 256; k < half * 256 + 256; ++k)
    s = fmaf(ctx[k], wv[(size_t)k * DV_ + vv], s);
  ps[t] = s;
  __syncthreads();
  if (t < 128) o_v[(size_t)b * (H_ * DV_) + h * DV_ + t] = ps[t] + ps[t + 128];
}

extern "C" void kernel_launch(void* const* d_in, const int* in_sizes, int n_in,
                              void* d_out, int out_size, void* d_ws, size_t ws_size,
                              hipStream_t stream) {
  const float* hs    = (const float*)d_in[0];
  const int*   pos   = (const int*)d_in[1];
  const float* cl    = (const float*)d_in[2];
  const float* cr    = (const float*)d_in[3];
  const float* w_qkv = (const float*)d_in[4];
  const float* qnw   = (const float*)d_in[5];
  const float* w_qb  = (const float*)d_in[6];
  const float* kvnw  = (const float*)d_in[7];
  const float* w_kc  = (const float*)d_in[8];
  const float* w_vc  = (const float*)d_in[9];
  const float* w_o   = (const float*)d_in[10];
  float* out = (float*)d_out;

  char* ws = (char*)d_ws;
  float* ws_acc   = (float*)(ws);                      // 16777216
  float* qkv_red  = (float*)(ws + 16777216);           // 270336
  float* qn       = (float*)(ws + 17047552);           // 196608
  float* latent_n = (float*)(ws + 17244160);           // 65536
  float* kpe_rot  = (float*)(ws + 17309696);           // 8192
  float* cs_buf   = (float*)(ws + 17317888);           // 8192
  float* qb_red   = (float*)(ws + 17326080);           // 393216
  unsigned short* q_cat = (unsigned short*)(ws + 17719296); // 589824
  float* ws_ml    = (float*)(ws + 18309120);           // 65536
  float* o_v      = (float*)(ws + 18374656);           // 262144

  zero3<<<640, 256, 0, stream>>>(qkv_red, B_ * NQKV_, qb_red, B_ * NQB_, out, B_ * HID_);
  gemm_at<HID_, 160, NQKV_><<<dim3(9, 32),  256, 0, stream>>>(hs, w_qkv, qkv_red);
  k2a<<<32, 256, 0, stream>>>(qkv_red, qnw, kvnw, pos, qn, latent_n, kpe_rot, cs_buf);
  gemm_at<QL_, 96, NQB_><<<dim3(12, 16), 256, 0, stream>>>(qn, w_qb, qb_red);
  k2c<<<dim3(16, 32), 64, 0, stream>>>(qb_red, w_kc, cs_buf, q_cat);
  attn<<<dim3(16, 32), 256, 0, stream>>>(cl, cr, latent_n, kpe_rot, q_cat, ws_acc, ws_ml);
  combine<<<dim3(16, 32), 256, 0, stream>>>(ws_acc, ws_ml, w_vc, o_v);
  gemm_at<H_ * DV_, 128, HID_><<<dim3(20, 16), 256, 0, stream>>>(o_v, w_o, out);
}

// Round 3
// 567.415 us; speedup vs baseline: 1.3840x; 1.2282x over previous
//
#include <hip/hip_runtime.h>
#include <stdint.h>

#define B_   32
#define S_   4096
#define HID_ 5120
#define H_   16
#define DN_  128
#define DR_  64
#define DV_  128
#define QL_  1536
#define KL_  512
#define KC_  576            // KL + DR
#define NQKV_ 2112          // QL + KL + DR
#define NQB_  3072          // H*(DN+DR)
#define EPS_ 1e-6f
#define SCALE_ 0.07216878364870323f   // (DN+DR)^-0.5

typedef __attribute__((ext_vector_type(4))) float f32x4;
typedef __attribute__((ext_vector_type(8))) short s16x8;
typedef __attribute__((ext_vector_type(4))) unsigned short u16x4;

__device__ __forceinline__ unsigned short f2bf(float f) {
  union { float f; unsigned u; } v; v.f = f;
  unsigned r = v.u + 0x7fffu + ((v.u >> 16) & 1u);
  return (unsigned short)(r >> 16);
}

// ---------------- cvt_bf: fp32 -> bf16 (vectorized) ----------------
__global__ void cvt_bf(const float* __restrict__ X, unsigned short* __restrict__ Y, int n4) {
  int i = blockIdx.x * 256 + threadIdx.x;
  if (i < n4) {
    float4 v = ((const float4*)X)[i];
    u16x4 o; o.x = f2bf(v.x); o.y = f2bf(v.y); o.z = f2bf(v.z); o.w = f2bf(v.w);
    ((u16x4*)Y)[i] = o;
  }
}

// ------------- MFMA split-K GEMM: P[ks][b][n] = sum_{k in slice} A[b][k]*W[k][n]
// A bf16 [32][K]; W fp32 [K][N] converted in-register. 4 waves = 64 n/block.
// No LDS, no atomics. D-layout: row=b=quad*4+reg(+16), col=n=n0+lo.
template<int K, int TK, int N>
__global__ __launch_bounds__(256) void gemm_bf(const unsigned short* __restrict__ Abf,
                                               const float* __restrict__ W,
                                               float* __restrict__ P) {
  int t = threadIdx.x, wave = t >> 6, lane = t & 63;
  int quad = lane >> 4, lo = lane & 15;
  int n0 = blockIdx.x * 64 + wave * 16;
  int k0 = blockIdx.y * TK;
  f32x4 acc0 = {0.f, 0.f, 0.f, 0.f}, acc1 = {0.f, 0.f, 0.f, 0.f};
  const float* wp = W + (size_t)(k0 + quad * 8) * N + n0 + lo;
  const unsigned short* a0p = Abf + (size_t)lo * K + k0 + quad * 8;
  const unsigned short* a1p = Abf + (size_t)(16 + lo) * K + k0 + quad * 8;
#pragma unroll 2
  for (int kk = 0; kk < TK / 32; ++kk) {
    s16x8 a0 = *(const s16x8*)(a0p + kk * 32);
    s16x8 a1 = *(const s16x8*)(a1p + kk * 32);
    float wv[8];
#pragma unroll
    for (int j = 0; j < 8; ++j) wv[j] = wp[((size_t)kk * 32 + j) * N];
    s16x8 bf;
#pragma unroll
    for (int j = 0; j < 8; ++j) bf[j] = (short)f2bf(wv[j]);
    acc0 = __builtin_amdgcn_mfma_f32_16x16x32_bf16(a0, bf, acc0, 0, 0, 0);
    acc1 = __builtin_amdgcn_mfma_f32_16x16x32_bf16(a1, bf, acc1, 0, 0, 0);
  }
  float* p = P + ((size_t)blockIdx.y * B_) * N + n0 + lo;
#pragma unroll
  for (int reg = 0; reg < 4; ++reg) {
    p[(size_t)(quad * 4 + reg) * N]      = acc0[reg];
    p[(size_t)(16 + quad * 4 + reg) * N] = acc1[reg];
  }
}

// ---------------- k2a: sum 16 k-slices, rmsnorms, rope(k_pe) ----------------
__global__ void k2a(const float* __restrict__ P1, const float* __restrict__ qw,
                    const float* __restrict__ kvw, const int* __restrict__ pos,
                    unsigned short* __restrict__ qn_bf, float* __restrict__ latent_n,
                    float* __restrict__ kpe_rot, float* __restrict__ cs_buf) {
  int b = blockIdx.x, t = threadIdx.x;
  __shared__ float row[NQKV_];
  __shared__ float red[256], red2[256];
  float sq = 0.f, sl = 0.f;
  for (int n = t; n < NQKV_; n += 256) {
    float s = 0.f;
#pragma unroll
    for (int ks = 0; ks < 16; ++ks) s += P1[((size_t)ks * B_ + b) * NQKV_ + n];
    row[n] = s;
    if (n < QL_) sq += s * s;
    else if (n < QL_ + KL_) sl += s * s;
  }
  red[t] = sq; red2[t] = sl;
  __syncthreads();
  for (int off = 128; off > 0; off >>= 1) {
    if (t < off) { red[t] += red[t + off]; red2[t] += red2[t + off]; }
    __syncthreads();
  }
  float rq = 1.0f / sqrtf(red[0]  / QL_ + EPS_);
  float rl = 1.0f / sqrtf(red2[0] / KL_ + EPS_);
  for (int n = t; n < QL_; n += 256) qn_bf[(size_t)b * QL_ + n] = f2bf(row[n] * rq * qw[n]);
  for (int n = t; n < KL_; n += 256) latent_n[(size_t)b * KL_ + n] = row[QL_ + n] * rl * kvw[n];
  if (t < 32) {
    double inv = exp(-((double)t / 32.0) * log(10000.0));
    float fr = (float)pos[b] * (float)inv;
    float c = (float)cos((double)fr), s = (float)sin((double)fr);
    cs_buf[(b * 32 + t) * 2] = c; cs_buf[(b * 32 + t) * 2 + 1] = s;
    float x1 = row[QL_ + KL_ + 2 * t], x2 = row[QL_ + KL_ + 2 * t + 1];
    kpe_rot[b * DR_ + 2 * t]     = x1 * c - x2 * s;
    kpe_rot[b * DR_ + 2 * t + 1] = x2 * c + x1 * s;
  }
}

// ---------------- k2c: sum 12 k-slices, rope(q_pe), q_abs = q_nope @ w_kc ----------------
// 256 thr = 4 waves, wave handles one head. grid (4, 32).
__global__ __launch_bounds__(256) void k2c(const float* __restrict__ P2,
                                           const float* __restrict__ w_kc,
                                           const float* __restrict__ cs_buf,
                                           unsigned short* __restrict__ q_cat) {
  int b = blockIdx.y, t = threadIdx.x, wave = t >> 6, lane = t & 63;
  int h = blockIdx.x * 4 + wave;
  __shared__ float qh[4][192];
  for (int j = lane; j < 192; j += 64) {
    float s = 0.f;
    int col = h * 192 + j;
#pragma unroll
    for (int ks = 0; ks < 12; ++ks) s += P2[((size_t)ks * B_ + b) * NQB_ + col];
    qh[wave][j] = s;
  }
  __syncthreads();
  if (lane < 32) {
    float c = cs_buf[(b * 32 + lane) * 2], s = cs_buf[(b * 32 + lane) * 2 + 1];
    float x1 = qh[wave][DN_ + 2 * lane], x2 = qh[wave][DN_ + 2 * lane + 1];
    qh[wave][DN_ + 2 * lane]     = x1 * c - x2 * s;
    qh[wave][DN_ + 2 * lane + 1] = x2 * c + x1 * s;
  }
  __syncthreads();
  float acc[8];
#pragma unroll
  for (int i = 0; i < 8; ++i) acc[i] = 0.f;
  const float* wk = w_kc + (size_t)h * DN_ * KL_;
#pragma unroll 2
  for (int d = 0; d < DN_; ++d) {
    float qd = qh[wave][d];
#pragma unroll
    for (int i = 0; i < 8; ++i)
      acc[i] = fmaf(qd, wk[(size_t)d * KL_ + lane + 64 * i], acc[i]);
  }
  unsigned short* qc = q_cat + ((size_t)b * H_ + h) * KC_;
#pragma unroll
  for (int i = 0; i < 8; ++i) qc[lane + 64 * i] = f2bf(acc[i] * SCALE_);
  qc[KL_ + lane] = f2bf(qh[wave][DN_ + lane] * SCALE_);
}

// ---------------- attn: flash attention (bf16 MFMA, online softmax) ----------------
#define LP_ 584          // LDS row pitch (bf16): 16B-aligned rows
#define CHUNK_ 256
#define TR_ 32
#define NTL_ 8

__global__ __launch_bounds__(256, 2) void attn(
    const float* __restrict__ cache_l, const float* __restrict__ cache_r,
    const float* __restrict__ latent_n, const float* __restrict__ kpe_rot,
    const unsigned short* __restrict__ q_cat,
    float* __restrict__ ws_acc, float* __restrict__ ws_ml) {
  int chunk = blockIdx.x, b = blockIdx.y;
  int t = threadIdx.x, wave = t >> 6, lane = t & 63;
  int quad = lane >> 4, lo = lane & 15;

  __shared__ __attribute__((aligned(16))) unsigned short Lt[TR_ * LP_];
  __shared__ __attribute__((aligned(16))) unsigned short pb[4][H_ * TR_];

  s16x8 af[18];
  const unsigned short* qc = q_cat + ((size_t)b * H_ + lo) * KC_;
#pragma unroll
  for (int ks = 0; ks < 18; ++ks) af[ks] = *(const s16x8*)(qc + ks * 32 + quad * 8);

  f32x4 accc[NTL_];
#pragma unroll
  for (int i = 0; i < NTL_; ++i) accc[i] = (f32x4){0.f, 0.f, 0.f, 0.f};
  float m_run[4], l_run[4];
#pragma unroll
  for (int r = 0; r < 4; ++r) { m_run[r] = -3.0e38f; l_run[r] = 0.f; }

  int r8 = t >> 3, u = t & 7;

  float4 v[18];
  auto load_tile = [&](int tile) {
    int s = chunk * CHUNK_ + tile * TR_ + r8;
    const float* rl = cache_l + ((size_t)b * S_ + s) * KL_;
    const float* rr = cache_r + ((size_t)b * S_ + s) * DR_;
    if (s == S_ - 1) { rl = latent_n + (size_t)b * KL_; rr = kpe_rot + (size_t)b * DR_; }
#pragma unroll
    for (int j = 0; j < 18; ++j) {
      int c = u * 4 + j * 32;
      v[j] = *(const float4*)((j < 16) ? (rl + c) : (rr + (c - 512)));
    }
  };
  load_tile(0);

#pragma unroll 1
  for (int tile = 0; tile < NTL_; ++tile) {
    __syncthreads();
#pragma unroll
    for (int j = 0; j < 18; ++j) {
      int c = u * 4 + j * 32;
      u16x4 o; o.x = f2bf(v[j].x); o.y = f2bf(v[j].y); o.z = f2bf(v[j].z); o.w = f2bf(v[j].w);
      *(u16x4*)(&Lt[r8 * LP_ + c]) = o;
    }
    if (tile + 1 < NTL_) load_tile(tile + 1);
    __syncthreads();
    f32x4 sc0 = {0.f, 0.f, 0.f, 0.f}, sc1 = {0.f, 0.f, 0.f, 0.f};
#pragma unroll
    for (int ks = 0; ks < 18; ++ks) {
      s16x8 b0 = *(const s16x8*)(&Lt[lo * LP_ + ks * 32 + quad * 8]);
      s16x8 b1 = *(const s16x8*)(&Lt[(16 + lo) * LP_ + ks * 32 + quad * 8]);
      sc0 = __builtin_amdgcn_mfma_f32_16x16x32_bf16(af[ks], b0, sc0, 0, 0, 0);
      sc1 = __builtin_amdgcn_mfma_f32_16x16x32_bf16(af[ks], b1, sc1, 0, 0, 0);
    }
#pragma unroll
    for (int reg = 0; reg < 4; ++reg) {
      float s0 = sc0[reg], s1 = sc1[reg];
      float mt = fmaxf(s0, s1);
#pragma unroll
      for (int m = 1; m < 16; m <<= 1) mt = fmaxf(mt, __shfl_xor(mt, m, 64));
      float mn = fmaxf(m_run[reg], mt);
      float alpha = __expf(m_run[reg] - mn);
      m_run[reg] = mn;
      float p0 = __expf(s0 - mn), p1 = __expf(s1 - mn);
      float lt = p0 + p1;
#pragma unroll
      for (int m = 1; m < 16; m <<= 1) lt += __shfl_xor(lt, m, 64);
      l_run[reg] = l_run[reg] * alpha + lt;
#pragma unroll
      for (int i = 0; i < NTL_; ++i) accc[i][reg] *= alpha;
      int h = quad * 4 + reg;
      pb[wave][h * TR_ + lo]      = f2bf(p0);
      pb[wave][h * TR_ + 16 + lo] = f2bf(p1);
    }
    s16x8 ap = *(const s16x8*)(&pb[wave][lo * TR_ + quad * 8]);
#pragma unroll
    for (int nt = 0; nt < NTL_; ++nt) {
      int c = wave * 128 + nt * 16 + lo;
      s16x8 bv;
#pragma unroll
      for (int j = 0; j < 8; ++j) bv[j] = (short)Lt[(quad * 8 + j) * LP_ + c];
      accc[nt] = __builtin_amdgcn_mfma_f32_16x16x32_bf16(ap, bv, accc[nt], 0, 0, 0);
    }
  }
  float* accp = ws_acc + (((size_t)b * 16 + chunk) * H_) * KL_;
#pragma unroll
  for (int nt = 0; nt < NTL_; ++nt) {
    int c = wave * 128 + nt * 16 + lo;
#pragma unroll
    for (int reg = 0; reg < 4; ++reg)
      accp[(size_t)(quad * 4 + reg) * KL_ + c] = accc[nt][reg];
  }
  if (wave == 0 && lo == 0) {
#pragma unroll
    for (int reg = 0; reg < 4; ++reg) {
      int h = quad * 4 + reg;
      ws_ml[(((size_t)b * 16 + chunk) * H_ + h) * 2 + 0] = m_run[reg];
      ws_ml[(((size_t)b * 16 + chunk) * H_ + h) * 2 + 1] = l_run[reg];
    }
  }
}

// ---------------- combine chunks + ctx @ w_vc ----------------
__global__ void combine(const float* __restrict__ ws_acc, const float* __restrict__ ws_ml,
                        const float* __restrict__ w_vc, unsigned short* __restrict__ o_v) {
  int h = blockIdx.x, b = blockIdx.y, t = threadIdx.x;
  __shared__ float sm[16], sl[16];
  __shared__ float ctx[KL_];
  __shared__ float ps[256];
  if (t < 16) {
    sm[t] = ws_ml[(((size_t)b * 16 + t) * H_ + h) * 2];
    sl[t] = ws_ml[(((size_t)b * 16 + t) * H_ + h) * 2 + 1];
  }
  __syncthreads();
  float M = -3e38f;
#pragma unroll
  for (int i = 0; i < 16; ++i) M = fmaxf(M, sm[i]);
  float wkk[16]; float Lsum = 0.f;
#pragma unroll
  for (int i = 0; i < 16; ++i) { wkk[i] = __expf(sm[i] - M); Lsum += wkk[i] * sl[i]; }
  float invL = 1.0f / Lsum;
  for (int c = t; c < KL_; c += 256) {
    float s = 0.f;
#pragma unroll
    for (int i = 0; i < 16; ++i)
      s += wkk[i] * ws_acc[(((size_t)b * 16 + i) * H_ + h) * KL_ + c];
    ctx[c] = s * invL;
  }
  __syncthreads();
  int vv = t & 127, half = t >> 7;
  const float* wv = w_vc + (size_t)h * KL_ * DV_;
  float s = 0.f;
#pragma unroll 4
  for (int k = half * 256; k < half * 256 + 256; ++k)
    s = fmaf(ctx[k], wv[(size_t)k * DV_ + vv], s);
  ps[t] = s;
  __syncthreads();
  if (t < 128) o_v[(size_t)b * (H_ * DV_) + h * DV_ + t] = f2bf(ps[t] + ps[t + 128]);
}

// ---------------- reduce_out: sum 8 k-slices of out projection ----------------
__global__ void reduce_out(const float* __restrict__ P, float* __restrict__ out) {
  int i = blockIdx.x * 256 + threadIdx.x;   // 32*5120
  float s = 0.f;
#pragma unroll
  for (int ks = 0; ks < 8; ++ks) s += P[(size_t)ks * (B_ * HID_) + i];
  out[i] = s;
}

extern "C" void kernel_launch(void* const* d_in, const int* in_sizes, int n_in,
                              void* d_out, int out_size, void* d_ws, size_t ws_size,
                              hipStream_t stream) {
  const float* hs    = (const float*)d_in[0];
  const int*   pos   = (const int*)d_in[1];
  const float* cl    = (const float*)d_in[2];
  const float* cr    = (const float*)d_in[3];
  const float* w_qkv = (const float*)d_in[4];
  const float* qnw   = (const float*)d_in[5];
  const float* w_qb  = (const float*)d_in[6];
  const float* kvnw  = (const float*)d_in[7];
  const float* w_kc  = (const float*)d_in[8];
  const float* w_vc  = (const float*)d_in[9];
  const float* w_o   = (const float*)d_in[10];
  float* out = (float*)d_out;

  char* ws = (char*)d_ws;
  float* ws_acc = (float*)(ws);                              // 16,777,216
  float* P1     = (float*)(ws + 16777216);                   // 16 x 32 x 2112 x4 = 4,325,376
  float* P2     = (float*)(ws + 21102592);                   // 12 x 32 x 3072 x4 = 4,718,592
  float* P5     = (float*)(ws + 25821184);                   //  8 x 32 x 5120 x4 = 5,242,880
  unsigned short* hs_bf = (unsigned short*)(ws + 31064064);  // 327,680
  unsigned short* qn_bf = (unsigned short*)(ws + 31391744);  // 98,304
  float* latent_n = (float*)(ws + 31490048);                 // 65,536
  float* kpe_rot  = (float*)(ws + 31555584);                 // 8,192
  float* cs_buf   = (float*)(ws + 31563776);                 // 8,192
  unsigned short* q_cat = (unsigned short*)(ws + 31571968);  // 589,824
  float* ws_ml    = (float*)(ws + 32161792);                 // 65,536
  unsigned short* o_v_bf = (unsigned short*)(ws + 32227328); // 131,072

  cvt_bf<<<160, 256, 0, stream>>>(hs, hs_bf, B_ * HID_ / 4);
  gemm_bf<HID_, 320, NQKV_><<<dim3(33, 16), 256, 0, stream>>>(hs_bf, w_qkv, P1);
  k2a<<<32, 256, 0, stream>>>(P1, qnw, kvnw, pos, qn_bf, latent_n, kpe_rot, cs_buf);
  gemm_bf<QL_, 128, NQB_><<<dim3(48, 12), 256, 0, stream>>>(qn_bf, w_qb, P2);
  k2c<<<dim3(4, 32), 256, 0, stream>>>(P2, w_kc, cs_buf, q_cat);
  attn<<<dim3(16, 32), 256, 0, stream>>>(cl, cr, latent_n, kpe_rot, q_cat, ws_acc, ws_ml);
  combine<<<dim3(16, 32), 256, 0, stream>>>(ws_acc, ws_ml, w_vc, o_v_bf);
  gemm_bf<H_ * DV_, 256, HID_><<<dim3(80, 8), 256, 0, stream>>>(o_v_bf, w_o, P5);
  reduce_out<<<640, 256, 0, stream>>>(P5, out);
}